// Round 2
// baseline (65922.504 us; speedup 1.0000x reference)
//
#include <hip/hip_runtime.h>
#include <math.h>

#define D 128
#define NH 16
#define HD 8
#define NLAYER 16
#define V 17
#define L 1024
#define BOSX 16
#define NHEAL 31

// ---- lat init: lat[0]=BOS, lat[1..1024]=tokens ----
__global__ void kInit(const int* __restrict__ tokens, int* __restrict__ lat) {
  int i = blockIdx.x * blockDim.x + threadIdx.x;
  if (i == 0) lat[0] = BOSX;
  if (i < L) lat[i + 1] = tokens[i];
}

// ---- embed rows [cs,ce]: h[row] = emb[lat[row]] + pos[row] ----
__global__ void kEmbedRows(const int* __restrict__ lat, const float* __restrict__ emb,
                           const float* __restrict__ pos, float* __restrict__ h,
                           const int* __restrict__ bounds, int bk) {
  int cs, ce;
  if (bk >= 0) { cs = bounds[2 * bk]; ce = bounds[2 * bk + 1]; }
  else { cs = 0; ce = L - 1; }
  int t = threadIdx.x;
  for (int row = cs + (int)blockIdx.x; row <= ce; row += (int)gridDim.x) {
    if (t < D) h[row * D + t] = emb[lat[row] * D + t] + pos[row * D + t];
  }
}

// ---- stage A: x=LN1(h[row]); qkv = x@wqkv + b; 8 rows per block ----
__global__ void kA(const float* __restrict__ h, const float* __restrict__ ln_s,
                   const float* __restrict__ ln_b, const float* __restrict__ wqkv,
                   const float* __restrict__ bqkv, float* __restrict__ qbuf,
                   float* __restrict__ kc, float* __restrict__ vc,
                   const int* __restrict__ bounds, int bk) {
  __shared__ float xT[D][8];  // transposed: xT[d][r]
  int cs, ce;
  if (bk >= 0) { cs = bounds[2 * bk]; ce = bounds[2 * bk + 1]; }
  else { cs = 0; ce = L - 1; }
  int row0 = cs + (int)blockIdx.x * 8;
  if (row0 > ce) return;
  int t = threadIdx.x;
  // LN1: 8 rows, 32 lanes per row
  {
    int r = t >> 5, lane = t & 31;
    int row = row0 + r; if (row > ce) row = ce;
    const float* hp = h + row * D;
    float v0 = hp[lane], v1 = hp[lane + 32], v2 = hp[lane + 64], v3 = hp[lane + 96];
    float s = v0 + v1 + v2 + v3;
#pragma unroll
    for (int o = 16; o; o >>= 1) s += __shfl_xor(s, o, 32);
    float mean = s * (1.f / 128.f);
    float d0 = v0 - mean, d1 = v1 - mean, d2 = v2 - mean, d3 = v3 - mean;
    float vs = d0 * d0 + d1 * d1 + d2 * d2 + d3 * d3;
#pragma unroll
    for (int o = 16; o; o >>= 1) vs += __shfl_xor(vs, o, 32);
    float rstd = rsqrtf(vs * (1.f / 128.f) + 1e-5f);
    xT[lane][r]      = d0 * rstd * ln_s[lane]      + ln_b[lane];
    xT[lane + 32][r] = d1 * rstd * ln_s[lane + 32] + ln_b[lane + 32];
    xT[lane + 64][r] = d2 * rstd * ln_s[lane + 64] + ln_b[lane + 64];
    xT[lane + 96][r] = d3 * rstd * ln_s[lane + 96] + ln_b[lane + 96];
  }
  __syncthreads();
  // GEMM: [8x128] @ [128x384]; thread -> cols {c,c+128,c+256}, rows rh*4..rh*4+3
  int rh = t >> 7;
  int c = t & 127;
  float acc0x=0,acc0y=0,acc0z=0,acc0w=0, acc1x=0,acc1y=0,acc1z=0,acc1w=0, acc2x=0,acc2y=0,acc2z=0,acc2w=0;
  const float4* xT4 = (const float4*)&xT[0][0];  // xT4[d*2 + rh]
  const float* wq = wqkv + c;
#pragma unroll 4
  for (int d = 0; d < D; ++d) {
    float4 xv = xT4[d * 2 + rh];
    float w0 = wq[d * 384];
    float w1 = wq[d * 384 + 128];
    float w2 = wq[d * 384 + 256];
    acc0x += xv.x * w0; acc0y += xv.y * w0; acc0z += xv.z * w0; acc0w += xv.w * w0;
    acc1x += xv.x * w1; acc1y += xv.y * w1; acc1z += xv.z * w1; acc1w += xv.w * w1;
    acc2x += xv.x * w2; acc2y += xv.y * w2; acc2z += xv.z * w2; acc2w += xv.w * w2;
  }
  float bq = bqkv[c], bkk = bqkv[c + 128], bv = bqkv[c + 256];
  float a0[4] = {acc0x, acc0y, acc0z, acc0w};
  float a1[4] = {acc1x, acc1y, acc1z, acc1w};
  float a2[4] = {acc2x, acc2y, acc2z, acc2w};
#pragma unroll
  for (int rr = 0; rr < 4; ++rr) {
    int row = row0 + rh * 4 + rr;
    if (row <= ce) {
      qbuf[row * D + c] = a0[rr] + bq;
      kc[row * D + c]   = a1[rr] + bkk;
      vc[row * D + c]   = a2[rr] + bv;
    }
  }
}

// ---- stage B: attention + proj + residual + LN2 + FF + residual; 4 rows/block ----
__global__ void kB(float* __restrict__ h, const float* __restrict__ qbuf,
                   const float* __restrict__ kc, const float* __restrict__ vc,
                   const float* __restrict__ wo, const float* __restrict__ bo,
                   const float* __restrict__ ln_s, const float* __restrict__ ln_b,
                   const float* __restrict__ w1, const float* __restrict__ b1,
                   const float* __restrict__ w2, const float* __restrict__ b2,
                   const int* __restrict__ bounds, int bk) {
  __shared__ float obufT[D][4];
  __shared__ float hrowT[D][4];
  __shared__ float xnT[D][4];
  __shared__ float fT[4 * D][4];
  int cs, ce;
  if (bk >= 0) { cs = bounds[2 * bk]; ce = bounds[2 * bk + 1]; }
  else { cs = 0; ce = L - 1; }
  int row0 = cs + (int)blockIdx.x * 4;
  if (row0 > ce) return;
  int t = threadIdx.x;
  // ---- attention: thread = (r, head, lane4). scores tiny -> exp without max-sub ----
  {
    int r = t >> 6;
    int sub = t & 63;
    int head = sub >> 2;
    int lane = sub & 3;
    int row = row0 + r; if (row > ce) row = ce;
    const float4* qp = (const float4*)(qbuf + row * D + head * HD);
    float4 q0 = qp[0], q1 = qp[1];
    float sum = 0.f;
    float a0x=0,a0y=0,a0z=0,a0w=0, a1x=0,a1y=0,a1z=0,a1w=0;
    for (int key = lane; key <= row; key += 4) {
      const float4* kp = (const float4*)(kc + key * D + head * HD);
      float4 k0 = kp[0], k1 = kp[1];
      float sc = q0.x * k0.x + q0.y * k0.y + q0.z * k0.z + q0.w * k0.w
               + q1.x * k1.x + q1.y * k1.y + q1.z * k1.z + q1.w * k1.w;
      float p = __expf(sc * 0.35355339059327376f);
      const float4* vp = (const float4*)(vc + key * D + head * HD);
      float4 v0 = vp[0], v1 = vp[1];
      sum += p;
      a0x += p * v0.x; a0y += p * v0.y; a0z += p * v0.z; a0w += p * v0.w;
      a1x += p * v1.x; a1y += p * v1.y; a1z += p * v1.z; a1w += p * v1.w;
    }
#pragma unroll
    for (int o = 1; o < 4; o <<= 1) {
      sum += __shfl_xor(sum, o, 4);
      a0x += __shfl_xor(a0x, o, 4); a0y += __shfl_xor(a0y, o, 4);
      a0z += __shfl_xor(a0z, o, 4); a0w += __shfl_xor(a0w, o, 4);
      a1x += __shfl_xor(a1x, o, 4); a1y += __shfl_xor(a1y, o, 4);
      a1z += __shfl_xor(a1z, o, 4); a1w += __shfl_xor(a1w, o, 4);
    }
    if (lane == 0) {
      float inv = 1.f / sum;
      obufT[head * HD + 0][r] = a0x * inv;
      obufT[head * HD + 1][r] = a0y * inv;
      obufT[head * HD + 2][r] = a0z * inv;
      obufT[head * HD + 3][r] = a0w * inv;
      obufT[head * HD + 4][r] = a1x * inv;
      obufT[head * HD + 5][r] = a1y * inv;
      obufT[head * HD + 6][r] = a1z * inv;
      obufT[head * HD + 7][r] = a1w * inv;
    }
  }
  __syncthreads();
  // ---- proj + residual -> hrowT (LDS only) ----
  {
    int rh = t >> 7;  // rows rh*2, rh*2+1
    int c = t & 127;
    float acc0 = 0.f, acc1 = 0.f;
    const float* wp = wo + c;
#pragma unroll 4
    for (int d = 0; d < D; ++d) {
      float2 ov = *(const float2*)&obufT[d][rh * 2];
      float w = wp[d * D];
      acc0 += ov.x * w; acc1 += ov.y * w;
    }
    float bov = bo[c];
    int rowa = row0 + rh * 2, rowb = rowa + 1;
    int rowac = rowa > ce ? ce : rowa, rowbc = rowb > ce ? ce : rowb;
    hrowT[c][rh * 2]     = h[rowac * D + c] + acc0 + bov;
    hrowT[c][rh * 2 + 1] = h[rowbc * D + c] + acc1 + bov;
  }
  __syncthreads();
  // ---- LN2: 4 rows, 64 lanes per row ----
  {
    int r = t >> 6, lane = t & 63;
    float v0 = hrowT[lane][r], v1 = hrowT[lane + 64][r];
    float s = v0 + v1;
#pragma unroll
    for (int o = 32; o; o >>= 1) s += __shfl_xor(s, o, 64);
    float mean = s * (1.f / 128.f);
    float d0 = v0 - mean, d1 = v1 - mean;
    float vs = d0 * d0 + d1 * d1;
#pragma unroll
    for (int o = 32; o; o >>= 1) vs += __shfl_xor(vs, o, 64);
    float rstd = rsqrtf(vs * (1.f / 128.f) + 1e-5f);
    xnT[lane][r]      = d0 * rstd * ln_s[lane]      + ln_b[lane];
    xnT[lane + 64][r] = d1 * rstd * ln_s[lane + 64] + ln_b[lane + 64];
  }
  __syncthreads();
  // ---- FF1 + gelu: cols {t, t+256}, 4 rows each ----
  {
    float accA[4] = {0.f, 0.f, 0.f, 0.f};
    float accB[4] = {0.f, 0.f, 0.f, 0.f};
    const float* w1p = w1 + t;
#pragma unroll 4
    for (int d = 0; d < D; ++d) {
      float4 xv = *(const float4*)&xnT[d][0];
      float wa = w1p[d * 512];
      float wb = w1p[d * 512 + 256];
      accA[0] += xv.x * wa; accA[1] += xv.y * wa; accA[2] += xv.z * wa; accA[3] += xv.w * wa;
      accB[0] += xv.x * wb; accB[1] += xv.y * wb; accB[2] += xv.z * wb; accB[3] += xv.w * wb;
    }
    float ba = b1[t], bb = b1[t + 256];
#pragma unroll
    for (int rr = 0; rr < 4; ++rr) {
      float a = accA[rr] + ba;
      float cg = 0.7978845608028654f * (a + 0.044715f * a * a * a);
      cg = fminf(fmaxf(cg, -15.f), 15.f);
      float e = __expf(2.f * cg);
      fT[t][rr] = 0.5f * a * (1.f + (e - 1.f) / (e + 1.f));
      float b = accB[rr] + bb;
      cg = 0.7978845608028654f * (b + 0.044715f * b * b * b);
      cg = fminf(fmaxf(cg, -15.f), 15.f);
      e = __expf(2.f * cg);
      fT[t + 256][rr] = 0.5f * b * (1.f + (e - 1.f) / (e + 1.f));
    }
  }
  __syncthreads();
  // ---- FF2 + residual ----
  {
    int rh = t >> 7;
    int c = t & 127;
    float acc0 = 0.f, acc1 = 0.f;
    const float* w2p = w2 + c;
#pragma unroll 4
    for (int d = 0; d < 4 * D; ++d) {
      float2 fv = *(const float2*)&fT[d][rh * 2];
      float w = w2p[d * D];
      acc0 += fv.x * w; acc1 += fv.y * w;
    }
    float bv = b2[c];
    int rowa = row0 + rh * 2, rowb = rowa + 1;
    if (rowa <= ce) h[rowa * D + c] = hrowT[c][rh * 2]     + acc0 + bv;
    if (rowb <= ce) h[rowb * D + c] = hrowT[c][rh * 2 + 1] + acc1 + bv;
  }
}

// ---- head: logits[row] = LNf(h[row]) @ head_w + head_b; 8 rows/block ----
__global__ void kHead(const float* __restrict__ h, const float* __restrict__ lnf_s,
                      const float* __restrict__ lnf_b, const float* __restrict__ hw,
                      const float* __restrict__ hb, float* __restrict__ logits,
                      const int* __restrict__ bounds, int bk) {
  __shared__ float xnT[D][8];
  int cs, ce;
  if (bk >= 0) { cs = bounds[2 * bk]; ce = bounds[2 * bk + 1]; }
  else { cs = 0; ce = L - 1; }
  int row0 = cs + (int)blockIdx.x * 8;
  if (row0 > ce) return;
  int t = threadIdx.x;
  {
    int r = t >> 5, lane = t & 31;
    int row = row0 + r; if (row > ce) row = ce;
    const float* hp = h + row * D;
    float v0 = hp[lane], v1 = hp[lane + 32], v2 = hp[lane + 64], v3 = hp[lane + 96];
    float s = v0 + v1 + v2 + v3;
#pragma unroll
    for (int o = 16; o; o >>= 1) s += __shfl_xor(s, o, 32);
    float mean = s * (1.f / 128.f);
    float d0 = v0 - mean, d1 = v1 - mean, d2 = v2 - mean, d3 = v3 - mean;
    float vs = d0 * d0 + d1 * d1 + d2 * d2 + d3 * d3;
#pragma unroll
    for (int o = 16; o; o >>= 1) vs += __shfl_xor(vs, o, 32);
    float rstd = rsqrtf(vs * (1.f / 128.f) + 1e-5f);
    xnT[lane][r]      = d0 * rstd * lnf_s[lane]      + lnf_b[lane];
    xnT[lane + 32][r] = d1 * rstd * lnf_s[lane + 32] + lnf_b[lane + 32];
    xnT[lane + 64][r] = d2 * rstd * lnf_s[lane + 64] + lnf_b[lane + 64];
    xnT[lane + 96][r] = d3 * rstd * lnf_s[lane + 96] + lnf_b[lane + 96];
  }
  __syncthreads();
  if (t < 8 * V) {
    int r = t / V, c = t % V;
    int row = row0 + r;
    if (row <= ce) {
      float a = 0.f;
#pragma unroll 8
      for (int d = 0; d < D; ++d) a += xnT[d][r] * hw[d * V + c];
      logits[row * V + c] = a + hb[c];
    }
  }
}

// ---- per-position next-token log-likelihood ----
__global__ void kLL(const float* __restrict__ logits, const int* __restrict__ lat,
                    float* __restrict__ ll) {
  int p = blockIdx.x * blockDim.x + threadIdx.x;
  if (p >= L) return;
  const float* r = logits + p * V;
  float m = r[0];
#pragma unroll
  for (int v = 1; v < V; ++v) m = fmaxf(m, r[v]);
  float s = 0.f;
#pragma unroll
  for (int v = 0; v < V; ++v) s += expf(r[v] - m);
  float lse = m + logf(s);
  ll[p] = r[lat[p + 1]] - lse;
}

// ---- sort ll, 3% quantile, build heal list + chunk bounds ----
__global__ void kSort(const float* __restrict__ ll, int* __restrict__ heal_row,
                      int* __restrict__ bounds) {
  __shared__ float s[L];
  int t = threadIdx.x;
  for (int i = t; i < L; i += 256) s[i] = ll[i];
  __syncthreads();
  for (int ksz = 2; ksz <= L; ksz <<= 1) {
    for (int j = ksz >> 1; j > 0; j >>= 1) {
      for (int i = t; i < L; i += 256) {
        int lidx = i ^ j;
        if (lidx > i) {
          bool up = ((i & ksz) == 0);
          float a = s[i], b = s[lidx];
          if ((a > b) == up) { s[i] = b; s[lidx] = a; }
        }
      }
      __syncthreads();
    }
  }
  if (t == 0) {
    double frac = 0.03 * 1023.0 - 30.0;  // 0.69
    float val = (float)((double)s[30] + frac * ((double)s[31] - (double)s[30]));
    int rows[NHEAL];
    int c = 0;
    for (int p = 0; p < L; ++p) {
      if (ll[p] < val) {
        if (c < NHEAL) rows[c] = p;
        ++c;
      }
    }
    if (c > NHEAL) c = NHEAL;
    for (int k = 0; k < NHEAL; ++k) {
      if (k < c) {
        heal_row[k] = rows[k];
        bounds[2 * k] = (k == 0) ? 1 : (rows[k - 1] + 1);  // chunk 0 never launched
        bounds[2 * k + 1] = (k == 0) ? 0 : rows[k];
      } else {
        heal_row[k] = -1;
        bounds[2 * k] = 1;
        bounds[2 * k + 1] = 0;
      }
    }
    heal_row[NHEAL] = -1;
    bounds[2 * NHEAL] = (c > 0) ? (rows[c - 1] + 1) : L;  // final tail chunk
    bounds[2 * NHEAL + 1] = L - 1;
  }
}

// ---- heal: argmax over logits row (excluding BOS), write lat ----
__global__ void kHeal(const float* __restrict__ logits, const int* __restrict__ heal_row,
                      int* __restrict__ lat, int k) {
  if (threadIdx.x != 0) return;
  int r = heal_row[k];
  if (r < 0) return;
  const float* row = logits + r * V;
  int best = 0;
  float bv = row[0];
  for (int v = 1; v < BOSX; ++v) {  // exclude v == BOS (16)
    if (row[v] > bv) { bv = row[v]; best = v; }
  }
  lat[r + 1] = best;
}

// ---- write healed tokens as float to d_out tail ----
__global__ void kTokens(const int* __restrict__ lat, float* __restrict__ out) {
  int i = blockIdx.x * blockDim.x + threadIdx.x;
  if (i < L) out[i] = (float)lat[i + 1];
}

extern "C" void kernel_launch(void* const* d_in, const int* in_sizes, int n_in,
                              void* d_out, int out_size, void* d_ws, size_t ws_size,
                              hipStream_t stream) {
  const int* tokens  = (const int*)d_in[0];
  const float* emb   = (const float*)d_in[1];
  const float* pos   = (const float*)d_in[2];
  const float* ln1_s = (const float*)d_in[3];
  const float* ln1_b = (const float*)d_in[4];
  const float* wqkv  = (const float*)d_in[5];
  const float* bqkv  = (const float*)d_in[6];
  const float* wo    = (const float*)d_in[7];
  const float* bo    = (const float*)d_in[8];
  const float* ln2_s = (const float*)d_in[9];
  const float* ln2_b = (const float*)d_in[10];
  const float* w1    = (const float*)d_in[11];
  const float* b1    = (const float*)d_in[12];
  const float* w2    = (const float*)d_in[13];
  const float* b2    = (const float*)d_in[14];
  const float* lnf_s = (const float*)d_in[15];
  const float* lnf_b = (const float*)d_in[16];
  const float* hw    = (const float*)d_in[17];
  const float* hb    = (const float*)d_in[18];

  // workspace layout (floats)
  float* h    = (float*)d_ws;              // L*D
  float* qbuf = h + L * D;                 // L*D
  float* kc   = qbuf + L * D;              // NLAYER*L*D
  float* vc   = kc + NLAYER * L * D;       // NLAYER*L*D
  float* ll   = vc + NLAYER * L * D;       // L
  int* lat    = (int*)(ll + L);            // 1025 (pad 1032)
  int* heal_row = lat + 1032;              // 32
  int* bounds   = heal_row + 32;           // 64

  float* logits = (float*)d_out;           // L*V
  float* out_tok = logits + L * V;         // L

  kInit<<<5, 256, 0, stream>>>(tokens, lat);

  // ---- Phase A: full pass ----
  kEmbedRows<<<256, 128, 0, stream>>>(lat, emb, pos, h, bounds, -1);
  for (int l = 0; l < NLAYER; ++l) {
    kA<<<128, 256, 0, stream>>>(h, ln1_s + l * D, ln1_b + l * D, wqkv + l * D * 3 * D,
                                bqkv + l * 3 * D, qbuf, kc + l * L * D, vc + l * L * D,
                                bounds, -1);
    kB<<<256, 256, 0, stream>>>(h, qbuf, kc + l * L * D, vc + l * L * D, wo + l * D * D,
                                bo + l * D, ln2_s + l * D, ln2_b + l * D,
                                w1 + l * D * 4 * D, b1 + l * 4 * D, w2 + l * 4 * D * D,
                                b2 + l * D, bounds, -1);
  }
  kHead<<<128, 256, 0, stream>>>(h, lnf_s, lnf_b, hw, hb, logits, bounds, -1);
  kLL<<<4, 256, 0, stream>>>(logits, lat, ll);
  kSort<<<1, 256, 0, stream>>>(ll, heal_row, bounds);

  // ---- heal 0 uses Phase A logits directly ----
  kHeal<<<1, 64, 0, stream>>>(logits, heal_row, lat, 0);

  // ---- heals 1..30: chunked KV-cache recompute ----
  for (int k = 1; k < NHEAL; ++k) {
    kEmbedRows<<<128, 128, 0, stream>>>(lat, emb, pos, h, bounds, k);
    for (int l = 0; l < NLAYER; ++l) {
      kA<<<128, 256, 0, stream>>>(h, ln1_s + l * D, ln1_b + l * D, wqkv + l * D * 3 * D,
                                  bqkv + l * 3 * D, qbuf, kc + l * L * D, vc + l * L * D,
                                  bounds, k);
      kB<<<256, 256, 0, stream>>>(h, qbuf, kc + l * L * D, vc + l * L * D, wo + l * D * D,
                                  bo + l * D, ln2_s + l * D, ln2_b + l * D,
                                  w1 + l * D * 4 * D, b1 + l * 4 * D, w2 + l * 4 * D * D,
                                  b2 + l * D, bounds, k);
    }
    kHead<<<128, 256, 0, stream>>>(h, lnf_s, lnf_b, hw, hb, logits, bounds, k);
    kHeal<<<1, 64, 0, stream>>>(logits, heal_row, lat, k);
  }

  // ---- final tail chunk (rows after last heal) ----
  kEmbedRows<<<128, 128, 0, stream>>>(lat, emb, pos, h, bounds, NHEAL);
  for (int l = 0; l < NLAYER; ++l) {
    kA<<<128, 256, 0, stream>>>(h, ln1_s + l * D, ln1_b + l * D, wqkv + l * D * 3 * D,
                                bqkv + l * 3 * D, qbuf, kc + l * L * D, vc + l * L * D,
                                bounds, NHEAL);
    kB<<<256, 256, 0, stream>>>(h, qbuf, kc + l * L * D, vc + l * L * D, wo + l * D * D,
                                bo + l * D, ln2_s + l * D, ln2_b + l * D,
                                w1 + l * D * 4 * D, b1 + l * 4 * D, w2 + l * 4 * D * D,
                                b2 + l * D, bounds, NHEAL);
  }
  kHead<<<128, 256, 0, stream>>>(h, lnf_s, lnf_b, hw, hb, logits, bounds, NHEAL);

  kTokens<<<4, 256, 0, stream>>>(lat, out_tok);
}